// Round 10
// baseline (367.659 us; speedup 1.0000x reference)
//
#include <hip/hip_runtime.h>
#include <stdint.h>

#define D    64
#define D2   128
#define R    98           // nodes per bucket  (1024*98 = 100352 >= N)
#define NBK  1024         // buckets
#define CAP  2176         // payload slots per bucket (mean 1562, +15 sigma;
                          // also >= 2144 = tri(2080)+s(64) in-place partial)
#define NTRI 2144         // upper-triangle M (2080) + column sum s (64)

// ---------------------------------------------------------------------------
// Fused setup: blocks 0..59 embsum, 60..75 bcursor init, 76..141 zero Mbar
// (Mbar is accumulated by k_redM via float atomics).
// ---------------------------------------------------------------------------
__global__ void k_embsum(
    const float* __restrict__ be0, const float* __restrict__ be1,
    const float* __restrict__ be2, float* __restrict__ embsum,
    int* __restrict__ bcursor, float* __restrict__ Mbar)
{
    int c = blockIdx.x;
    int t = threadIdx.x;     // 0..63
    if (c < 60) {
        int f0 = c / 12;
        int r  = c % 12;
        int f1 = r / 2;
        int f2 = r % 2;
        embsum[c * D + t] = be0[f0 * D + t] + be1[f1 * D + t] + be2[f2 * D + t];
    } else if (c < 76) {
        int i = (c - 60) * 64 + t;
        if (i < NBK) bcursor[i * 16] = i * CAP;
    } else {
        int i = (c - 76) * 64 + t;     // 0..4223
        Mbar[i] = 0.0f;
    }
}

// ---------------------------------------------------------------------------
// Bucket partition: tile of 4096 edges per block, 512 threads, LDS-staged
// contiguous flush. payload word: src | (code<<17) | (localdst<<23)
// ---------------------------------------------------------------------------
__global__ __launch_bounds__(512) void k_part(
    const int* __restrict__ ei, const int* __restrict__ ef,
    int* __restrict__ bcursor, int* __restrict__ payload, int E)
{
    __shared__ int scnt[NBK];            // per-tile bucket counts (4 KB)
    __shared__ int sstart[NBK];          // exclusive scan of scnt (4 KB)
    __shared__ int sgbase[NBK];          // reserved global base per bucket (4 KB)
    __shared__ int sdat[4096];           // staged payload words (16 KB)
    __shared__ unsigned short sbkt[4096];// bucket of each staged slot (8 KB)
    __shared__ int sred2[512];           // block-scan partials (2 KB)

    int t = threadIdx.x;
    for (int i = t; i < NBK; i += 512) scnt[i] = 0;
    __syncthreads();

    int base2 = blockIdx.x * 2048;       // pair index base (2 edges/pair)

    int b0[4], p0[4], r0[4];
    int b1[4], p1[4], r1[4];

    #pragma unroll
    for (int k = 0; k < 4; k++) {
        int i2 = base2 + k * 512 + t;
        int e0 = i2 * 2;
        if (e0 < E) {
            int2 d  = ((const int2*)ei)[i2];
            int2 s  = ((const int2*)(ei + E))[i2];
            int2 q0 = ((const int2*)ef)[3 * i2 + 0];
            int2 q1 = ((const int2*)ef)[3 * i2 + 1];
            int2 q2 = ((const int2*)ef)[3 * i2 + 2];
            {
                int bb = d.x / R; if (bb > NBK - 1) bb = NBK - 1;
                int ld = d.x - bb * R;
                int code = q0.x * 12 + q0.y * 2 + q1.x;
                b0[k] = bb;
                p0[k] = s.x | (code << 17) | (ld << 23);
                r0[k] = atomicAdd(&scnt[bb], 1);
            }
            if (e0 + 1 < E) {
                int bb = d.y / R; if (bb > NBK - 1) bb = NBK - 1;
                int ld = d.y - bb * R;
                int code = q1.y * 12 + q2.x * 2 + q2.y;
                b1[k] = bb;
                p1[k] = s.y | (code << 17) | (ld << 23);
                r1[k] = atomicAdd(&scnt[bb], 1);
            }
        }
    }
    __syncthreads();

    // exclusive scan of scnt[0..NBK-1]: thread t owns 2 consecutive buckets
    int c0 = scnt[t * 2], c1 = scnt[t * 2 + 1];
    sred2[t] = c0 + c1;
    __syncthreads();
    int sv = sred2[t];
    for (int off = 1; off < 512; off <<= 1) {
        int x = (t >= off) ? sred2[t - off] : 0;
        __syncthreads();
        sred2[t] += x;
        __syncthreads();
    }
    int excl = sred2[t] - sv;
    sstart[t * 2]     = excl;
    sstart[t * 2 + 1] = excl + c0;
    __syncthreads();

    // reserve global space: one atomic per non-empty bucket (padded cursors)
    for (int i = t; i < NBK; i += 512) {
        int c = scnt[i];
        if (c) sgbase[i] = atomicAdd(&bcursor[i * 16], c);
    }
    __syncthreads();

    // place edges into staged slots (dense: sstart[b] + rank)
    #pragma unroll
    for (int k = 0; k < 4; k++) {
        int i2 = base2 + k * 512 + t;
        int e0 = i2 * 2;
        if (e0 < E) {
            int slot = sstart[b0[k]] + r0[k];
            sdat[slot] = p0[k]; sbkt[slot] = (unsigned short)b0[k];
            if (e0 + 1 < E) {
                slot = sstart[b1[k]] + r1[k];
                sdat[slot] = p1[k]; sbkt[slot] = (unsigned short)b1[k];
            }
        }
    }
    __syncthreads();

    // flush: thread-linear over staged slots -> contiguous runs per bucket
    int tc = E - base2 * 2; if (tc > 4096) tc = 4096;
    #pragma unroll
    for (int k = 0; k < 8; k++) {
        int i = k * 512 + t;
        if (i < tc) {
            int bb = sbkt[i];
            int pos = sgbase[bb] + (i - sstart[bb]);
            if (pos < (bb + 1) * CAP) payload[pos] = sdat[i];
        }
    }
}

// ---------------------------------------------------------------------------
// Per-bucket, fused (internals byte-identical to round 9); bucket offset b0
// allows 2-dispatch split for profiling visibility (blocks independent).
// ---------------------------------------------------------------------------
__global__ __launch_bounds__(512, 8) void k_sortred(
    const float* __restrict__ nf,
    const int* __restrict__ bcursor,
    int* __restrict__ payload,
    const float* __restrict__ embsum,
    const float* __restrict__ epsp,
    float* __restrict__ h, int N, int b0)
{
    __shared__ float sE[60 * D];     // 15360 B
    __shared__ int   sq[CAP];        // 8704 B  sorted payload
    __shared__ int   scn[R + 1];     // node start offsets
    __shared__ int   scur[R];        // scatter cursors
    __shared__ int   sscan[128];     // scan workspace

    int tid = threadIdx.x;
    int b = b0 + blockIdx.x;
    int n0 = b * R;

    for (int i = tid; i < 60 * D; i += 512) sE[i] = embsum[i];
    if (tid <= R) scn[tid] = 0;
    __syncthreads();

    int js = b * CAP;
    int cnt = bcursor[b * 16] - js;
    if (cnt > CAP) cnt = CAP;
    if (cnt < 0) cnt = 0;

    // pass 1: count per node (scalar int LDS atomics at scn[ld+1])
    for (int i = tid; i < cnt; i += 512)
        atomicAdd(&scn[((unsigned)payload[js + i] >> 23) + 1], 1);
    __syncthreads();

    // inclusive scan over 128 entries (R+1=99 live)
    if (tid < 128) sscan[tid] = (tid <= R) ? scn[tid] : 0;
    __syncthreads();
    for (int off = 1; off < 128; off <<= 1) {
        int x = 0;
        if (tid < 128 && tid >= off) x = sscan[tid - off];
        __syncthreads();
        if (tid < 128) sscan[tid] += x;
        __syncthreads();
    }
    if (tid <= R) {
        scn[tid] = sscan[tid];
        if (tid < R) scur[tid] = sscan[tid];
    }
    __syncthreads();

    // pass 2: re-read payload, scatter into sorted LDS order
    for (int i = tid; i < cnt; i += 512) {
        int u = payload[js + i];
        int pos = atomicAdd(&scur[(unsigned)u >> 23], 1);
        sq[pos] = u;
    }
    __syncthreads();

    // wave-per-node register-accumulate reduce
    int w = tid >> 6, l = tid & 63;
    float epsv = 1.0f + epsp[0];
    for (int r = w; r < R; r += 8) {
        int n = n0 + r;
        if (n >= N) break;
        int st = scn[r], en = scn[r + 1];
        float acc = 0.0f;
        for (int jb = st; jb < en; jb += 64) {
            int u = (jb + l < en) ? sq[jb + l] : 0;
            int m = en - jb; if (m > 64) m = 64;
            int t = 0;
            for (; t + 4 <= m; t += 4) {
                int a0 = __shfl(u, t + 0);
                int a1 = __shfl(u, t + 1);
                int a2 = __shfl(u, t + 2);
                int a3 = __shfl(u, t + 3);
                float x0 = nf[(size_t)(a0 & 0x1FFFF) * D + l];
                float x1 = nf[(size_t)(a1 & 0x1FFFF) * D + l];
                float x2 = nf[(size_t)(a2 & 0x1FFFF) * D + l];
                float x3 = nf[(size_t)(a3 & 0x1FFFF) * D + l];
                float e0 = sE[((a0 >> 17) & 63) * D + l];
                float e1 = sE[((a1 >> 17) & 63) * D + l];
                float e2 = sE[((a2 >> 17) & 63) * D + l];
                float e3 = sE[((a3 >> 17) & 63) * D + l];
                acc += fmaxf(x0 + e0, 0.0f) + fmaxf(x1 + e1, 0.0f)
                     + fmaxf(x2 + e2, 0.0f) + fmaxf(x3 + e3, 0.0f);
            }
            for (; t < m; t++) {
                int a = __shfl(u, t);
                acc += fmaxf(nf[(size_t)(a & 0x1FFFF) * D + l]
                             + sE[((a >> 17) & 63) * D + l], 0.0f);
            }
        }
        h[(size_t)n * D + l] = fmaf(epsv, nf[(size_t)n * D + l], acc);
    }
    __syncthreads();

    // phase 2: syrk partial over own rows, direct global reads (L2-hot).
    float* P = (float*)(payload + (size_t)b * CAP);
    const float4* h4 = (const float4*)h;
    if (tid < 256) {
        int iB = tid >> 4, jB = tid & 15;
        float M[4][4];
        #pragma unroll
        for (int a = 0; a < 4; a++)
            #pragma unroll
            for (int c = 0; c < 4; c++) M[a][c] = 0.0f;
        #pragma unroll 2
        for (int n2 = 0; n2 < R; n2++) {
            int n = n0 + n2;
            if (n >= N) break;
            float4 a = h4[(size_t)n * 16 + iB];
            float4 c = h4[(size_t)n * 16 + jB];
            M[0][0] = fmaf(a.x, c.x, M[0][0]);
            M[0][1] = fmaf(a.x, c.y, M[0][1]);
            M[0][2] = fmaf(a.x, c.z, M[0][2]);
            M[0][3] = fmaf(a.x, c.w, M[0][3]);
            M[1][0] = fmaf(a.y, c.x, M[1][0]);
            M[1][1] = fmaf(a.y, c.y, M[1][1]);
            M[1][2] = fmaf(a.y, c.z, M[1][2]);
            M[1][3] = fmaf(a.y, c.w, M[1][3]);
            M[2][0] = fmaf(a.z, c.x, M[2][0]);
            M[2][1] = fmaf(a.z, c.y, M[2][1]);
            M[2][2] = fmaf(a.z, c.z, M[2][2]);
            M[2][3] = fmaf(a.z, c.w, M[2][3]);
            M[3][0] = fmaf(a.w, c.x, M[3][0]);
            M[3][1] = fmaf(a.w, c.y, M[3][1]);
            M[3][2] = fmaf(a.w, c.z, M[3][2]);
            M[3][3] = fmaf(a.w, c.w, M[3][3]);
        }
        #pragma unroll
        for (int a = 0; a < 4; a++)
            #pragma unroll
            for (int c = 0; c < 4; c++) {
                int gi = iB * 4 + a, gj = jB * 4 + c;
                if (gi <= gj)
                    P[gi * 64 + gj - ((gi * (gi + 1)) >> 1)] = M[a][c];
            }
    } else if (tid < 320) {
        int lc = tid - 256;
        float s = 0.0f;
        for (int n2 = 0; n2 < R; n2++) {
            int n = n0 + n2;
            if (n >= N) break;
            s += h[(size_t)n * D + lc];
        }
        P[2080 + lc] = s;
    }
}

// ---------------------------------------------------------------------------
// Reduce per-bucket triangle partials -> full 64x64 M + sbar, atomically
// accumulated into pre-zeroed Mbar. 260 blocks (4 bucket-quarters x 65
// e-chunks) so all CUs participate (was 65 blocks = 25% of machine).
// ---------------------------------------------------------------------------
__global__ __launch_bounds__(512) void k_redM(
    const float* __restrict__ pM,
    float* __restrict__ Mbar, float invN)
{
    __shared__ float sred[512];
    int tid = threadIdx.x;
    int eq = tid & 63, bq = tid >> 6;
    int ec = blockIdx.x >> 2;              // 0..64
    int qg = blockIdx.x & 3;               // bucket quarter
    int e  = ec * 64 + eq;                 // 0..4159

    int src;
    if (e < 4096) {
        int i = e >> 6, j = e & 63;
        int a = i < j ? i : j;
        int b2 = i < j ? j : i;
        src = a * 64 + b2 - ((a * (a + 1)) >> 1);
    } else {
        src = 2080 + (e - 4096);
    }

    int bbase = qg * 256;
    float s0 = 0.0f, s1 = 0.0f, s2 = 0.0f, s3 = 0.0f;
    for (int b = bq; b < 256; b += 32) {
        s0 += pM[(size_t)(bbase + b +  0) * CAP + src];
        s1 += pM[(size_t)(bbase + b +  8) * CAP + src];
        s2 += pM[(size_t)(bbase + b + 16) * CAP + src];
        s3 += pM[(size_t)(bbase + b + 24) * CAP + src];
    }
    sred[tid] = (s0 + s1) + (s2 + s3);
    __syncthreads();
    if (tid < 64) {
        float s = 0.0f;
        #pragma unroll
        for (int q = 0; q < 8; q++) s += sred[q * 64 + tid];
        atomicAdd(&Mbar[e], s * invN);
    }
}

// Per-channel BN scale/shift, parallel: one block per channel (128 blocks x
// 64 threads). var_c = w^T M w - (w.sbar)^2, mean = w.sbar + b1.
__global__ __launch_bounds__(64) void k_bn(
    const float* __restrict__ Mbar,   // [4160]: full M then sbar
    const float* __restrict__ W1,     // [128,64]
    const float* __restrict__ b1,
    const float* __restrict__ gamma, const float* __restrict__ beta,
    float* __restrict__ ss)
{
    int c = blockIdx.x;               // channel 0..127
    int k = threadIdx.x;              // 0..63

    float wk = W1[c * D + k];
    float dk = wk * Mbar[4096 + k];

    float tk = 0.0f;
    #pragma unroll 8
    for (int j = 0; j < 64; j++)
        tk = fmaf(Mbar[k * 64 + j], W1[c * D + j], tk);
    float qk = wk * tk;

    // wave64 butterfly reductions
    #pragma unroll
    for (int off = 32; off > 0; off >>= 1) {
        dk += __shfl_xor(dk, off);
        qk += __shfl_xor(qk, off);
    }

    if (k == 0) {
        float var  = fmaxf(qk - dk * dk, 0.0f);
        float mean = dk + b1[c];
        float sc   = gamma[c] * rsqrtf(var + 1e-5f);
        ss[c]       = sc;
        ss[128 + c] = beta[c] - mean * sc;
    }
}

// ---------------------------------------------------------------------------
// GEMM2: persistent blocks, 128-row tiles, 512 threads (round-9 structure);
// tile range [tBeg,tEnd) allows 2-dispatch split for profiling visibility.
// LDS = AB 128x132 + W1t 32K + W2t 32K = 130 KB -> 1 block/CU, 8 waves.
// ---------------------------------------------------------------------------
#define ABS 132
__global__ __launch_bounds__(512) void k_gemm2(
    const float* __restrict__ h,
    const float* __restrict__ W1,    // [128,64]
    const float* __restrict__ b1,    // [128]
    const float* __restrict__ ss,    // scale/shift [256]
    const float* __restrict__ W2,    // [64,128]
    const float* __restrict__ b2v,   // [64]
    float* __restrict__ out,         // [N,64]
    int N, int tBeg, int tEnd)
{
    __shared__ float AB[128 * ABS];  // h tile then g tile (128x128 used)
    __shared__ float W1t[64 * 128];
    __shared__ float W2t[128 * 64];

    int tid = threadIdx.x;

    {   // stage W1^T: W1t[k][c], 512 threads
        int c  = tid >> 2;               // 0..127
        int k0 = (tid & 3) * 16;         // 0,16,32,48
        const float4* wr = (const float4*)(W1 + c * D + k0);
        #pragma unroll
        for (int q = 0; q < 4; q++) {
            float4 u = wr[q];
            int k = k0 + q * 4;
            W1t[(k + 0) * 128 + c] = u.x;
            W1t[(k + 1) * 128 + c] = u.y;
            W1t[(k + 2) * 128 + c] = u.z;
            W1t[(k + 3) * 128 + c] = u.w;
        }
    }
    {   // stage W2^T: W2t[k][j], 512 threads
        int j  = tid >> 3;               // 0..63
        int k0 = (tid & 7) * 16;         // 0..112
        const float4* wr = (const float4*)(W2 + j * D2 + k0);
        #pragma unroll
        for (int q = 0; q < 4; q++) {
            float4 u = wr[q];
            int k = k0 + q * 4;
            W2t[(k + 0) * 64 + j] = u.x;
            W2t[(k + 1) * 64 + j] = u.y;
            W2t[(k + 2) * 64 + j] = u.z;
            W2t[(k + 3) * 64 + j] = u.w;
        }
    }

    // GEMM1 mapping: rg 0..15 (8 rows each), cg 0..31 (4 cols each)
    int rg = tid >> 5, cg = tid & 31;
    float bb0 = b1[cg * 4 + 0];
    float bb1 = b1[cg * 4 + 1];
    float bb2 = b1[cg * 4 + 2];
    float bb3 = b1[cg * 4 + 3];
    float4 scv = *(const float4*)&ss[cg * 4];
    float4 shv = *(const float4*)&ss[128 + cg * 4];

    // GEMM2 mapping: r2 0..31 (4 rows each), c2 0..15 (4 cols each)
    int r2 = tid >> 4, c2 = tid & 15;
    float4 obv = *(const float4*)&b2v[c2 * 4];

    // staging mapping: r 0..127, c16 in {0,16,32,48}
    int sr = tid >> 2;
    int sc16 = (tid & 3) * 16;

    // prefetch first tile
    float4 pf[4];
    #pragma unroll
    for (int q = 0; q < 4; q++) pf[q] = make_float4(0.f, 0.f, 0.f, 0.f);
    {
        int gr = (tBeg + blockIdx.x) * 128 + sr;
        if (gr < N) {
            const float4* hrow = (const float4*)(h + (size_t)gr * D + sc16);
            #pragma unroll
            for (int q = 0; q < 4; q++) pf[q] = hrow[q];
        }
    }

    for (int t = tBeg + blockIdx.x; t < tEnd; t += gridDim.x) {
        int row0 = t * 128;
        __syncthreads();                 // prev GEMM2's AB reads done
        {   // write prefetched h tile
            float* dstp = &AB[sr * ABS + sc16];
            #pragma unroll
            for (int q = 0; q < 4; q++) ((float4*)dstp)[q] = pf[q];
        }
        __syncthreads();

        // GEMM1: rows rg*8+i, cols cg*4
        float acc[8][4];
        #pragma unroll
        for (int i = 0; i < 8; i++)
            #pragma unroll
            for (int j = 0; j < 4; j++) acc[i][j] = 0.0f;

        #pragma unroll 2
        for (int k4 = 0; k4 < 16; k4++) {
            float4 w0 = *(const float4*)&W1t[(k4 * 4 + 0) * 128 + cg * 4];
            float4 w1 = *(const float4*)&W1t[(k4 * 4 + 1) * 128 + cg * 4];
            float4 w2 = *(const float4*)&W1t[(k4 * 4 + 2) * 128 + cg * 4];
            float4 w3 = *(const float4*)&W1t[(k4 * 4 + 3) * 128 + cg * 4];
            #pragma unroll
            for (int i = 0; i < 8; i++) {
                float4 a = *(const float4*)&AB[(rg * 8 + i) * ABS + k4 * 4];
                acc[i][0] = fmaf(a.x, w0.x, acc[i][0]);
                acc[i][1] = fmaf(a.x, w0.y, acc[i][1]);
                acc[i][2] = fmaf(a.x, w0.z, acc[i][2]);
                acc[i][3] = fmaf(a.x, w0.w, acc[i][3]);
                acc[i][0] = fmaf(a.y, w1.x, acc[i][0]);
                acc[i][1] = fmaf(a.y, w1.y, acc[i][1]);
                acc[i][2] = fmaf(a.y, w1.z, acc[i][2]);
                acc[i][3] = fmaf(a.y, w1.w, acc[i][3]);
                acc[i][0] = fmaf(a.z, w2.x, acc[i][0]);
                acc[i][1] = fmaf(a.z, w2.y, acc[i][1]);
                acc[i][2] = fmaf(a.z, w2.z, acc[i][2]);
                acc[i][3] = fmaf(a.z, w2.w, acc[i][3]);
                acc[i][0] = fmaf(a.w, w3.x, acc[i][0]);
                acc[i][1] = fmaf(a.w, w3.y, acc[i][1]);
                acc[i][2] = fmaf(a.w, w3.z, acc[i][2]);
                acc[i][3] = fmaf(a.w, w3.w, acc[i][3]);
            }
        }
        __syncthreads();                 // h-cols of AB free

        // T14: issue next tile's h loads (hide under epilogue + GEMM2)
        int tn = t + gridDim.x;
        #pragma unroll
        for (int q = 0; q < 4; q++) pf[q] = make_float4(0.f, 0.f, 0.f, 0.f);
        if (tn < tEnd) {
            int gr = tn * 128 + sr;
            if (gr < N) {
                const float4* hrow = (const float4*)(h + (size_t)gr * D + sc16);
                #pragma unroll
                for (int q = 0; q < 4; q++) pf[q] = hrow[q];
            }
        }

        // bn + relu epilogue -> g overwrites AB (full 128 cols)
        #pragma unroll
        for (int i = 0; i < 8; i++) {
            float g0 = fmaxf(fmaf(acc[i][0] + bb0, scv.x, shv.x), 0.0f);
            float g1 = fmaxf(fmaf(acc[i][1] + bb1, scv.y, shv.y), 0.0f);
            float g2 = fmaxf(fmaf(acc[i][2] + bb2, scv.z, shv.z), 0.0f);
            float g3 = fmaxf(fmaf(acc[i][3] + bb3, scv.w, shv.w), 0.0f);
            *(float4*)&AB[(rg * 8 + i) * ABS + cg * 4] = make_float4(g0, g1, g2, g3);
        }
        __syncthreads();

        // GEMM2: rows r2*4+i, cols c2*4, K=128, all-b128 reads
        float acc2[4][4];
        #pragma unroll
        for (int i = 0; i < 4; i++)
            #pragma unroll
            for (int j = 0; j < 4; j++) acc2[i][j] = 0.0f;

        #pragma unroll 2
        for (int k4 = 0; k4 < 32; k4++) {
            float4 u0 = *(const float4*)&W2t[(k4 * 4 + 0) * 64 + c2 * 4];
            float4 u1 = *(const float4*)&W2t[(k4 * 4 + 1) * 64 + c2 * 4];
            float4 u2 = *(const float4*)&W2t[(k4 * 4 + 2) * 64 + c2 * 4];
            float4 u3 = *(const float4*)&W2t[(k4 * 4 + 3) * 64 + c2 * 4];
            #pragma unroll
            for (int i = 0; i < 4; i++) {
                float4 g = *(const float4*)&AB[(r2 * 4 + i) * ABS + k4 * 4];
                acc2[i][0] = fmaf(g.x, u0.x, acc2[i][0]);
                acc2[i][1] = fmaf(g.x, u0.y, acc2[i][1]);
                acc2[i][2] = fmaf(g.x, u0.z, acc2[i][2]);
                acc2[i][3] = fmaf(g.x, u0.w, acc2[i][3]);
                acc2[i][0] = fmaf(g.y, u1.x, acc2[i][0]);
                acc2[i][1] = fmaf(g.y, u1.y, acc2[i][1]);
                acc2[i][2] = fmaf(g.y, u1.z, acc2[i][2]);
                acc2[i][3] = fmaf(g.y, u1.w, acc2[i][3]);
                acc2[i][0] = fmaf(g.z, u2.x, acc2[i][0]);
                acc2[i][1] = fmaf(g.z, u2.y, acc2[i][1]);
                acc2[i][2] = fmaf(g.z, u2.z, acc2[i][2]);
                acc2[i][3] = fmaf(g.z, u2.w, acc2[i][3]);
                acc2[i][0] = fmaf(g.w, u3.x, acc2[i][0]);
                acc2[i][1] = fmaf(g.w, u3.y, acc2[i][1]);
                acc2[i][2] = fmaf(g.w, u3.z, acc2[i][2]);
                acc2[i][3] = fmaf(g.w, u3.w, acc2[i][3]);
            }
        }

        #pragma unroll
        for (int i = 0; i < 4; i++) {
            int gr = row0 + r2 * 4 + i;
            if (gr < N) {
                float4 pk = make_float4(acc2[i][0] + obv.x, acc2[i][1] + obv.y,
                                        acc2[i][2] + obv.z, acc2[i][3] + obv.w);
                *(float4*)&out[(size_t)gr * D + c2 * 4] = pk;
            }
        }
    }
}

// ---------------------------------------------------------------------------
extern "C" void kernel_launch(void* const* d_in, const int* in_sizes, int n_in,
                              void* d_out, int out_size, void* d_ws, size_t ws_size,
                              hipStream_t stream)
{
    const float* nf    = (const float*)d_in[0];
    const int*   ef    = (const int*)d_in[1];
    const int*   ei    = (const int*)d_in[2];
    const float* epsp  = (const float*)d_in[5];
    const float* be0   = (const float*)d_in[6];
    const float* be1   = (const float*)d_in[7];
    const float* be2   = (const float*)d_in[8];
    const float* W1    = (const float*)d_in[9];
    const float* b1    = (const float*)d_in[10];
    const float* gamma = (const float*)d_in[11];
    const float* beta  = (const float*)d_in[12];
    const float* W2    = (const float*)d_in[13];
    const float* b2v   = (const float*)d_in[14];
    float*       out   = (float*)d_out;

    int N = in_sizes[0] / D;    // 100000
    int E = in_sizes[1] / 3;    // 1600000

    int tiles2 = (N + 127) / 128;         // 782 (128-row tiles)
    int tMid   = (tiles2 + 1) / 2;        // 391

    // workspace layout (4-byte elements); per-bucket tri-M/s partials live
    // in-place in the payload region (dead after k_sortred's LDS sort)
    float* h       = (float*)d_ws;                    // N*64
    float* Mbar    = h + (size_t)N * D;               // 4224: full M + sbar
    float* ss      = Mbar + 4224;                     // 256
    float* embsum  = ss + 256;                        // 60*64
    int*   bcursor = (int*)(embsum + 60 * D);         // NBK*16 (line-padded)
    int*   payload = bcursor + NBK * 16;              // NBK*CAP (8.9 MB)
    float* pM      = (float*)payload;                 // stride CAP per bucket

    k_embsum<<<142, 64, 0, stream>>>(be0, be1, be2, embsum, bcursor, Mbar);

    int E2 = (E + 1) / 2;
    int gP = (E2 + 2047) / 2048;          // 391 tiles of 4096 edges
    k_part<<<gP, 512, 0, stream>>>(ei, ef, bcursor, payload, E);

    // split for profiling visibility (blocks fully independent)
    k_sortred<<<NBK / 2, 512, 0, stream>>>(nf, bcursor, payload, embsum, epsp, h, N, 0);
    k_sortred<<<NBK / 2, 512, 0, stream>>>(nf, bcursor, payload, embsum, epsp, h, N, NBK / 2);

    k_redM<<<260, 512, 0, stream>>>(pM, Mbar, 1.0f / (float)N);
    k_bn<<<128, 64, 0, stream>>>(Mbar, W1, b1, gamma, beta, ss);

    // split for profiling visibility
    k_gemm2<<<256, 512, 0, stream>>>(h, W1, b1, ss, W2, b2v, out, N, 0, tMid);
    k_gemm2<<<256, 512, 0, stream>>>(h, W1, b1, ss, W2, b2v, out, N, tMid, tiles2);
}

// Round 11
// 306.486 us; speedup vs baseline: 1.1996x; 1.1996x over previous
//
#include <hip/hip_runtime.h>
#include <stdint.h>

#define D    64
#define D2   128
#define R    98           // nodes per bucket  (1024*98 = 100352 >= N)
#define NBK  1024         // buckets
#define CAP  2176         // payload slots per bucket (mean 1562, +15 sigma;
                          // also >= 2144 = tri(2080)+s(64) in-place partial)

// ---------------------------------------------------------------------------
// Fused setup: blocks 0..59 embsum, 60..75 bcursor init, 76..141 zero Mbar
// (Mbar is accumulated by k_redM via float atomics).
// ---------------------------------------------------------------------------
__global__ void k_embsum(
    const float* __restrict__ be0, const float* __restrict__ be1,
    const float* __restrict__ be2, float* __restrict__ embsum,
    int* __restrict__ bcursor, float* __restrict__ Mbar)
{
    int c = blockIdx.x;
    int t = threadIdx.x;     // 0..63
    if (c < 60) {
        int f0 = c / 12;
        int r  = c % 12;
        int f1 = r / 2;
        int f2 = r % 2;
        embsum[c * D + t] = be0[f0 * D + t] + be1[f1 * D + t] + be2[f2 * D + t];
    } else if (c < 76) {
        int i = (c - 60) * 64 + t;
        if (i < NBK) bcursor[i * 16] = i * CAP;
    } else {
        int i = (c - 76) * 64 + t;     // 0..4223
        Mbar[i] = 0.0f;
    }
}

// ---------------------------------------------------------------------------
// Bucket partition: tile of 4096 edges per block, 512 threads, LDS-staged
// contiguous flush. payload word: src | (code<<17) | (localdst<<23)
// ---------------------------------------------------------------------------
__global__ __launch_bounds__(512) void k_part(
    const int* __restrict__ ei, const int* __restrict__ ef,
    int* __restrict__ bcursor, int* __restrict__ payload, int E)
{
    __shared__ int scnt[NBK];            // per-tile bucket counts (4 KB)
    __shared__ int sstart[NBK];          // exclusive scan of scnt (4 KB)
    __shared__ int sgbase[NBK];          // reserved global base per bucket (4 KB)
    __shared__ int sdat[4096];           // staged payload words (16 KB)
    __shared__ unsigned short sbkt[4096];// bucket of each staged slot (8 KB)
    __shared__ int sred2[512];           // block-scan partials (2 KB)

    int t = threadIdx.x;
    for (int i = t; i < NBK; i += 512) scnt[i] = 0;
    __syncthreads();

    int base2 = blockIdx.x * 2048;       // pair index base (2 edges/pair)

    int b0[4], p0[4], r0[4];
    int b1[4], p1[4], r1[4];

    #pragma unroll
    for (int k = 0; k < 4; k++) {
        int i2 = base2 + k * 512 + t;
        int e0 = i2 * 2;
        if (e0 < E) {
            int2 d  = ((const int2*)ei)[i2];
            int2 s  = ((const int2*)(ei + E))[i2];
            int2 q0 = ((const int2*)ef)[3 * i2 + 0];
            int2 q1 = ((const int2*)ef)[3 * i2 + 1];
            int2 q2 = ((const int2*)ef)[3 * i2 + 2];
            {
                int bb = d.x / R; if (bb > NBK - 1) bb = NBK - 1;
                int ld = d.x - bb * R;
                int code = q0.x * 12 + q0.y * 2 + q1.x;
                b0[k] = bb;
                p0[k] = s.x | (code << 17) | (ld << 23);
                r0[k] = atomicAdd(&scnt[bb], 1);
            }
            if (e0 + 1 < E) {
                int bb = d.y / R; if (bb > NBK - 1) bb = NBK - 1;
                int ld = d.y - bb * R;
                int code = q1.y * 12 + q2.x * 2 + q2.y;
                b1[k] = bb;
                p1[k] = s.y | (code << 17) | (ld << 23);
                r1[k] = atomicAdd(&scnt[bb], 1);
            }
        }
    }
    __syncthreads();

    // exclusive scan of scnt[0..NBK-1]: thread t owns 2 consecutive buckets
    int c0 = scnt[t * 2], c1 = scnt[t * 2 + 1];
    sred2[t] = c0 + c1;
    __syncthreads();
    int sv = sred2[t];
    for (int off = 1; off < 512; off <<= 1) {
        int x = (t >= off) ? sred2[t - off] : 0;
        __syncthreads();
        sred2[t] += x;
        __syncthreads();
    }
    int excl = sred2[t] - sv;
    sstart[t * 2]     = excl;
    sstart[t * 2 + 1] = excl + c0;
    __syncthreads();

    // reserve global space: one atomic per non-empty bucket (padded cursors)
    for (int i = t; i < NBK; i += 512) {
        int c = scnt[i];
        if (c) sgbase[i] = atomicAdd(&bcursor[i * 16], c);
    }
    __syncthreads();

    // place edges into staged slots (dense: sstart[b] + rank)
    #pragma unroll
    for (int k = 0; k < 4; k++) {
        int i2 = base2 + k * 512 + t;
        int e0 = i2 * 2;
        if (e0 < E) {
            int slot = sstart[b0[k]] + r0[k];
            sdat[slot] = p0[k]; sbkt[slot] = (unsigned short)b0[k];
            if (e0 + 1 < E) {
                slot = sstart[b1[k]] + r1[k];
                sdat[slot] = p1[k]; sbkt[slot] = (unsigned short)b1[k];
            }
        }
    }
    __syncthreads();

    // flush: thread-linear over staged slots -> contiguous runs per bucket
    int tc = E - base2 * 2; if (tc > 4096) tc = 4096;
    #pragma unroll
    for (int k = 0; k < 8; k++) {
        int i = k * 512 + t;
        if (i < tc) {
            int bb = sbkt[i];
            int pos = sgbase[bb] + (i - sstart[bb]);
            if (pos < (bb + 1) * CAP) payload[pos] = sdat[i];
        }
    }
}

// ---------------------------------------------------------------------------
// Per-bucket, fused:
//  1) counting-sort payload by localdst + register-accumulate reduce -> h
//     (gather loop 8-way unrolled: round-10 A/B showed throughput scales
//      ~linearly with outstanding requests -> more MLP per wave)
//  2) syrk partial over own 98 h rows -> tri M + col-sum s in dead payload.
// LDS ~25.4 KB, 512 thr -> 4 blocks/CU = 32 waves (HW cap); grid = 1024.
// ---------------------------------------------------------------------------
__global__ __launch_bounds__(512, 8) void k_sortred(
    const float* __restrict__ nf,
    const int* __restrict__ bcursor,
    int* __restrict__ payload,
    const float* __restrict__ embsum,
    const float* __restrict__ epsp,
    float* __restrict__ h, int N)
{
    __shared__ float sE[60 * D];     // 15360 B
    __shared__ int   sq[CAP];        // 8704 B  sorted payload
    __shared__ int   scn[R + 1];     // node start offsets
    __shared__ int   scur[R];        // scatter cursors
    __shared__ int   sscan[128];     // scan workspace

    int tid = threadIdx.x;
    int b = blockIdx.x;
    int n0 = b * R;

    for (int i = tid; i < 60 * D; i += 512) sE[i] = embsum[i];
    if (tid <= R) scn[tid] = 0;
    __syncthreads();

    int js = b * CAP;
    int cnt = bcursor[b * 16] - js;
    if (cnt > CAP) cnt = CAP;
    if (cnt < 0) cnt = 0;

    // pass 1: count per node (scalar int LDS atomics at scn[ld+1])
    for (int i = tid; i < cnt; i += 512)
        atomicAdd(&scn[((unsigned)payload[js + i] >> 23) + 1], 1);
    __syncthreads();

    // inclusive scan over 128 entries (R+1=99 live)
    if (tid < 128) sscan[tid] = (tid <= R) ? scn[tid] : 0;
    __syncthreads();
    for (int off = 1; off < 128; off <<= 1) {
        int x = 0;
        if (tid < 128 && tid >= off) x = sscan[tid - off];
        __syncthreads();
        if (tid < 128) sscan[tid] += x;
        __syncthreads();
    }
    if (tid <= R) {
        scn[tid] = sscan[tid];
        if (tid < R) scur[tid] = sscan[tid];
    }
    __syncthreads();

    // pass 2: re-read payload, scatter into sorted LDS order
    for (int i = tid; i < cnt; i += 512) {
        int u = payload[js + i];
        int pos = atomicAdd(&scur[(unsigned)u >> 23], 1);
        sq[pos] = u;
    }
    __syncthreads();

    // wave-per-node register-accumulate reduce; 8 outstanding gathers
    int w = tid >> 6, l = tid & 63;
    float epsv = 1.0f + epsp[0];
    for (int r = w; r < R; r += 8) {
        int n = n0 + r;
        if (n >= N) break;
        int st = scn[r], en = scn[r + 1];
        float acc = 0.0f;
        for (int jb = st; jb < en; jb += 64) {
            int u = (jb + l < en) ? sq[jb + l] : 0;
            int m = en - jb; if (m > 64) m = 64;
            int t = 0;
            for (; t + 8 <= m; t += 8) {
                int a0 = __shfl(u, t + 0);
                int a1 = __shfl(u, t + 1);
                int a2 = __shfl(u, t + 2);
                int a3 = __shfl(u, t + 3);
                int a4 = __shfl(u, t + 4);
                int a5 = __shfl(u, t + 5);
                int a6 = __shfl(u, t + 6);
                int a7 = __shfl(u, t + 7);
                float x0 = nf[(size_t)(a0 & 0x1FFFF) * D + l];
                float x1 = nf[(size_t)(a1 & 0x1FFFF) * D + l];
                float x2 = nf[(size_t)(a2 & 0x1FFFF) * D + l];
                float x3 = nf[(size_t)(a3 & 0x1FFFF) * D + l];
                float x4 = nf[(size_t)(a4 & 0x1FFFF) * D + l];
                float x5 = nf[(size_t)(a5 & 0x1FFFF) * D + l];
                float x6 = nf[(size_t)(a6 & 0x1FFFF) * D + l];
                float x7 = nf[(size_t)(a7 & 0x1FFFF) * D + l];
                float e0 = sE[((a0 >> 17) & 63) * D + l];
                float e1 = sE[((a1 >> 17) & 63) * D + l];
                float e2 = sE[((a2 >> 17) & 63) * D + l];
                float e3 = sE[((a3 >> 17) & 63) * D + l];
                float e4 = sE[((a4 >> 17) & 63) * D + l];
                float e5 = sE[((a5 >> 17) & 63) * D + l];
                float e6 = sE[((a6 >> 17) & 63) * D + l];
                float e7 = sE[((a7 >> 17) & 63) * D + l];
                acc += fmaxf(x0 + e0, 0.0f) + fmaxf(x1 + e1, 0.0f)
                     + fmaxf(x2 + e2, 0.0f) + fmaxf(x3 + e3, 0.0f)
                     + fmaxf(x4 + e4, 0.0f) + fmaxf(x5 + e5, 0.0f)
                     + fmaxf(x6 + e6, 0.0f) + fmaxf(x7 + e7, 0.0f);
            }
            for (; t + 4 <= m; t += 4) {
                int a0 = __shfl(u, t + 0);
                int a1 = __shfl(u, t + 1);
                int a2 = __shfl(u, t + 2);
                int a3 = __shfl(u, t + 3);
                float x0 = nf[(size_t)(a0 & 0x1FFFF) * D + l];
                float x1 = nf[(size_t)(a1 & 0x1FFFF) * D + l];
                float x2 = nf[(size_t)(a2 & 0x1FFFF) * D + l];
                float x3 = nf[(size_t)(a3 & 0x1FFFF) * D + l];
                float e0 = sE[((a0 >> 17) & 63) * D + l];
                float e1 = sE[((a1 >> 17) & 63) * D + l];
                float e2 = sE[((a2 >> 17) & 63) * D + l];
                float e3 = sE[((a3 >> 17) & 63) * D + l];
                acc += fmaxf(x0 + e0, 0.0f) + fmaxf(x1 + e1, 0.0f)
                     + fmaxf(x2 + e2, 0.0f) + fmaxf(x3 + e3, 0.0f);
            }
            for (; t < m; t++) {
                int a = __shfl(u, t);
                acc += fmaxf(nf[(size_t)(a & 0x1FFFF) * D + l]
                             + sE[((a >> 17) & 63) * D + l], 0.0f);
            }
        }
        h[(size_t)n * D + l] = fmaf(epsv, nf[(size_t)n * D + l], acc);
    }
    __syncthreads();

    // phase 2: syrk partial over own rows, direct global reads (L2-hot).
    float* P = (float*)(payload + (size_t)b * CAP);
    const float4* h4 = (const float4*)h;
    if (tid < 256) {
        int iB = tid >> 4, jB = tid & 15;
        float M[4][4];
        #pragma unroll
        for (int a = 0; a < 4; a++)
            #pragma unroll
            for (int c = 0; c < 4; c++) M[a][c] = 0.0f;
        #pragma unroll 2
        for (int n2 = 0; n2 < R; n2++) {
            int n = n0 + n2;
            if (n >= N) break;
            float4 a = h4[(size_t)n * 16 + iB];
            float4 c = h4[(size_t)n * 16 + jB];
            M[0][0] = fmaf(a.x, c.x, M[0][0]);
            M[0][1] = fmaf(a.x, c.y, M[0][1]);
            M[0][2] = fmaf(a.x, c.z, M[0][2]);
            M[0][3] = fmaf(a.x, c.w, M[0][3]);
            M[1][0] = fmaf(a.y, c.x, M[1][0]);
            M[1][1] = fmaf(a.y, c.y, M[1][1]);
            M[1][2] = fmaf(a.y, c.z, M[1][2]);
            M[1][3] = fmaf(a.y, c.w, M[1][3]);
            M[2][0] = fmaf(a.z, c.x, M[2][0]);
            M[2][1] = fmaf(a.z, c.y, M[2][1]);
            M[2][2] = fmaf(a.z, c.z, M[2][2]);
            M[2][3] = fmaf(a.z, c.w, M[2][3]);
            M[3][0] = fmaf(a.w, c.x, M[3][0]);
            M[3][1] = fmaf(a.w, c.y, M[3][1]);
            M[3][2] = fmaf(a.w, c.z, M[3][2]);
            M[3][3] = fmaf(a.w, c.w, M[3][3]);
        }
        #pragma unroll
        for (int a = 0; a < 4; a++)
            #pragma unroll
            for (int c = 0; c < 4; c++) {
                int gi = iB * 4 + a, gj = jB * 4 + c;
                if (gi <= gj)
                    P[gi * 64 + gj - ((gi * (gi + 1)) >> 1)] = M[a][c];
            }
    } else if (tid < 320) {
        int lc = tid - 256;
        float s = 0.0f;
        for (int n2 = 0; n2 < R; n2++) {
            int n = n0 + n2;
            if (n >= N) break;
            s += h[(size_t)n * D + lc];
        }
        P[2080 + lc] = s;
    }
}

// ---------------------------------------------------------------------------
// Reduce per-bucket triangle partials -> full 64x64 M + sbar, atomically
// accumulated into pre-zeroed Mbar. 260 blocks (4 bucket-quarters x 65
// e-chunks) so all CUs participate.
// ---------------------------------------------------------------------------
__global__ __launch_bounds__(512) void k_redM(
    const float* __restrict__ pM,
    float* __restrict__ Mbar, float invN)
{
    __shared__ float sred[512];
    int tid = threadIdx.x;
    int eq = tid & 63, bq = tid >> 6;
    int ec = blockIdx.x >> 2;              // 0..64
    int qg = blockIdx.x & 3;               // bucket quarter
    int e  = ec * 64 + eq;                 // 0..4159

    int src;
    if (e < 4096) {
        int i = e >> 6, j = e & 63;
        int a = i < j ? i : j;
        int b2 = i < j ? j : i;
        src = a * 64 + b2 - ((a * (a + 1)) >> 1);
    } else {
        src = 2080 + (e - 4096);
    }

    int bbase = qg * 256;
    float s0 = 0.0f, s1 = 0.0f, s2 = 0.0f, s3 = 0.0f;
    for (int b = bq; b < 256; b += 32) {
        s0 += pM[(size_t)(bbase + b +  0) * CAP + src];
        s1 += pM[(size_t)(bbase + b +  8) * CAP + src];
        s2 += pM[(size_t)(bbase + b + 16) * CAP + src];
        s3 += pM[(size_t)(bbase + b + 24) * CAP + src];
    }
    sred[tid] = (s0 + s1) + (s2 + s3);
    __syncthreads();
    if (tid < 64) {
        float s = 0.0f;
        #pragma unroll
        for (int q = 0; q < 8; q++) s += sred[q * 64 + tid];
        atomicAdd(&Mbar[e], s * invN);
    }
}

// Per-channel BN scale/shift, parallel: one block per channel (128 blocks x
// 64 threads). var_c = w^T M w - (w.sbar)^2, mean = w.sbar + b1.
__global__ __launch_bounds__(64) void k_bn(
    const float* __restrict__ Mbar,   // [4160]: full M then sbar
    const float* __restrict__ W1,     // [128,64]
    const float* __restrict__ b1,
    const float* __restrict__ gamma, const float* __restrict__ beta,
    float* __restrict__ ss)
{
    int c = blockIdx.x;               // channel 0..127
    int k = threadIdx.x;              // 0..63

    float wk = W1[c * D + k];
    float dk = wk * Mbar[4096 + k];

    float tk = 0.0f;
    #pragma unroll 8
    for (int j = 0; j < 64; j++)
        tk = fmaf(Mbar[k * 64 + j], W1[c * D + j], tk);
    float qk = wk * tk;

    // wave64 butterfly reductions
    #pragma unroll
    for (int off = 32; off > 0; off >>= 1) {
        dk += __shfl_xor(dk, off);
        qk += __shfl_xor(qk, off);
    }

    if (k == 0) {
        float var  = fmaxf(qk - dk * dk, 0.0f);
        float mean = dk + b1[c];
        float sc   = gamma[c] * rsqrtf(var + 1e-5f);
        ss[c]       = sc;
        ss[128 + c] = beta[c] - mean * sc;
    }
}

// ---------------------------------------------------------------------------
// GEMM2: persistent blocks, 128-row tiles, 512 threads (round-9 structure).
// LDS = AB 128x132 + W1t 32K + W2t 32K = 130 KB -> 1 block/CU, 8 waves.
// ---------------------------------------------------------------------------
#define ABS 132
__global__ __launch_bounds__(512) void k_gemm2(
    const float* __restrict__ h,
    const float* __restrict__ W1,    // [128,64]
    const float* __restrict__ b1,    // [128]
    const float* __restrict__ ss,    // scale/shift [256]
    const float* __restrict__ W2,    // [64,128]
    const float* __restrict__ b2v,   // [64]
    float* __restrict__ out,         // [N,64]
    int N, int tiles)
{
    __shared__ float AB[128 * ABS];  // h tile then g tile (128x128 used)
    __shared__ float W1t[64 * 128];
    __shared__ float W2t[128 * 64];

    int tid = threadIdx.x;

    {   // stage W1^T: W1t[k][c], 512 threads
        int c  = tid >> 2;               // 0..127
        int k0 = (tid & 3) * 16;         // 0,16,32,48
        const float4* wr = (const float4*)(W1 + c * D + k0);
        #pragma unroll
        for (int q = 0; q < 4; q++) {
            float4 u = wr[q];
            int k = k0 + q * 4;
            W1t[(k + 0) * 128 + c] = u.x;
            W1t[(k + 1) * 128 + c] = u.y;
            W1t[(k + 2) * 128 + c] = u.z;
            W1t[(k + 3) * 128 + c] = u.w;
        }
    }
    {   // stage W2^T: W2t[k][j], 512 threads
        int j  = tid >> 3;               // 0..63
        int k0 = (tid & 7) * 16;         // 0..112
        const float4* wr = (const float4*)(W2 + j * D2 + k0);
        #pragma unroll
        for (int q = 0; q < 4; q++) {
            float4 u = wr[q];
            int k = k0 + q * 4;
            W2t[(k + 0) * 64 + j] = u.x;
            W2t[(k + 1) * 64 + j] = u.y;
            W2t[(k + 2) * 64 + j] = u.z;
            W2t[(k + 3) * 64 + j] = u.w;
        }
    }

    // GEMM1 mapping: rg 0..15 (8 rows each), cg 0..31 (4 cols each)
    int rg = tid >> 5, cg = tid & 31;
    float bb0 = b1[cg * 4 + 0];
    float bb1 = b1[cg * 4 + 1];
    float bb2 = b1[cg * 4 + 2];
    float bb3 = b1[cg * 4 + 3];
    float4 scv = *(const float4*)&ss[cg * 4];
    float4 shv = *(const float4*)&ss[128 + cg * 4];

    // GEMM2 mapping: r2 0..31 (4 rows each), c2 0..15 (4 cols each)
    int r2 = tid >> 4, c2 = tid & 15;
    float4 obv = *(const float4*)&b2v[c2 * 4];

    // staging mapping: r 0..127, c16 in {0,16,32,48}
    int sr = tid >> 2;
    int sc16 = (tid & 3) * 16;

    // prefetch first tile
    float4 pf[4];
    #pragma unroll
    for (int q = 0; q < 4; q++) pf[q] = make_float4(0.f, 0.f, 0.f, 0.f);
    {
        int gr = blockIdx.x * 128 + sr;
        if (gr < N) {
            const float4* hrow = (const float4*)(h + (size_t)gr * D + sc16);
            #pragma unroll
            for (int q = 0; q < 4; q++) pf[q] = hrow[q];
        }
    }

    for (int t = blockIdx.x; t < tiles; t += gridDim.x) {
        int row0 = t * 128;
        __syncthreads();                 // prev GEMM2's AB reads done
        {   // write prefetched h tile
            float* dstp = &AB[sr * ABS + sc16];
            #pragma unroll
            for (int q = 0; q < 4; q++) ((float4*)dstp)[q] = pf[q];
        }
        __syncthreads();

        // GEMM1: rows rg*8+i, cols cg*4
        float acc[8][4];
        #pragma unroll
        for (int i = 0; i < 8; i++)
            #pragma unroll
            for (int j = 0; j < 4; j++) acc[i][j] = 0.0f;

        #pragma unroll 2
        for (int k4 = 0; k4 < 16; k4++) {
            float4 w0 = *(const float4*)&W1t[(k4 * 4 + 0) * 128 + cg * 4];
            float4 w1 = *(const float4*)&W1t[(k4 * 4 + 1) * 128 + cg * 4];
            float4 w2 = *(const float4*)&W1t[(k4 * 4 + 2) * 128 + cg * 4];
            float4 w3 = *(const float4*)&W1t[(k4 * 4 + 3) * 128 + cg * 4];
            #pragma unroll
            for (int i = 0; i < 8; i++) {
                float4 a = *(const float4*)&AB[(rg * 8 + i) * ABS + k4 * 4];
                acc[i][0] = fmaf(a.x, w0.x, acc[i][0]);
                acc[i][1] = fmaf(a.x, w0.y, acc[i][1]);
                acc[i][2] = fmaf(a.x, w0.z, acc[i][2]);
                acc[i][3] = fmaf(a.x, w0.w, acc[i][3]);
                acc[i][0] = fmaf(a.y, w1.x, acc[i][0]);
                acc[i][1] = fmaf(a.y, w1.y, acc[i][1]);
                acc[i][2] = fmaf(a.y, w1.z, acc[i][2]);
                acc[i][3] = fmaf(a.y, w1.w, acc[i][3]);
                acc[i][0] = fmaf(a.z, w2.x, acc[i][0]);
                acc[i][1] = fmaf(a.z, w2.y, acc[i][1]);
                acc[i][2] = fmaf(a.z, w2.z, acc[i][2]);
                acc[i][3] = fmaf(a.z, w2.w, acc[i][3]);
                acc[i][0] = fmaf(a.w, w3.x, acc[i][0]);
                acc[i][1] = fmaf(a.w, w3.y, acc[i][1]);
                acc[i][2] = fmaf(a.w, w3.z, acc[i][2]);
                acc[i][3] = fmaf(a.w, w3.w, acc[i][3]);
            }
        }
        __syncthreads();                 // h-cols of AB free

        // T14: issue next tile's h loads (hide under epilogue + GEMM2)
        int tn = t + gridDim.x;
        #pragma unroll
        for (int q = 0; q < 4; q++) pf[q] = make_float4(0.f, 0.f, 0.f, 0.f);
        if (tn < tiles) {
            int gr = tn * 128 + sr;
            if (gr < N) {
                const float4* hrow = (const float4*)(h + (size_t)gr * D + sc16);
                #pragma unroll
                for (int q = 0; q < 4; q++) pf[q] = hrow[q];
            }
        }

        // bn + relu epilogue -> g overwrites AB (full 128 cols)
        #pragma unroll
        for (int i = 0; i < 8; i++) {
            float g0 = fmaxf(fmaf(acc[i][0] + bb0, scv.x, shv.x), 0.0f);
            float g1 = fmaxf(fmaf(acc[i][1] + bb1, scv.y, shv.y), 0.0f);
            float g2 = fmaxf(fmaf(acc[i][2] + bb2, scv.z, shv.z), 0.0f);
            float g3 = fmaxf(fmaf(acc[i][3] + bb3, scv.w, shv.w), 0.0f);
            *(float4*)&AB[(rg * 8 + i) * ABS + cg * 4] = make_float4(g0, g1, g2, g3);
        }
        __syncthreads();

        // GEMM2: rows r2*4+i, cols c2*4, K=128, all-b128 reads
        float acc2[4][4];
        #pragma unroll
        for (int i = 0; i < 4; i++)
            #pragma unroll
            for (int j = 0; j < 4; j++) acc2[i][j] = 0.0f;

        #pragma unroll 2
        for (int k4 = 0; k4 < 32; k4++) {
            float4 u0 = *(const float4*)&W2t[(k4 * 4 + 0) * 64 + c2 * 4];
            float4 u1 = *(const float4*)&W2t[(k4 * 4 + 1) * 64 + c2 * 4];
            float4 u2 = *(const float4*)&W2t[(k4 * 4 + 2) * 64 + c2 * 4];
            float4 u3 = *(const float4*)&W2t[(k4 * 4 + 3) * 64 + c2 * 4];
            #pragma unroll
            for (int i = 0; i < 4; i++) {
                float4 g = *(const float4*)&AB[(r2 * 4 + i) * ABS + k4 * 4];
                acc2[i][0] = fmaf(g.x, u0.x, acc2[i][0]);
                acc2[i][1] = fmaf(g.x, u0.y, acc2[i][1]);
                acc2[i][2] = fmaf(g.x, u0.z, acc2[i][2]);
                acc2[i][3] = fmaf(g.x, u0.w, acc2[i][3]);
                acc2[i][0] = fmaf(g.y, u1.x, acc2[i][0]);
                acc2[i][1] = fmaf(g.y, u1.y, acc2[i][1]);
                acc2[i][2] = fmaf(g.y, u1.z, acc2[i][2]);
                acc2[i][3] = fmaf(g.y, u1.w, acc2[i][3]);
                acc2[i][0] = fmaf(g.z, u2.x, acc2[i][0]);
                acc2[i][1] = fmaf(g.z, u2.y, acc2[i][1]);
                acc2[i][2] = fmaf(g.z, u2.z, acc2[i][2]);
                acc2[i][3] = fmaf(g.z, u2.w, acc2[i][3]);
                acc2[i][0] = fmaf(g.w, u3.x, acc2[i][0]);
                acc2[i][1] = fmaf(g.w, u3.y, acc2[i][1]);
                acc2[i][2] = fmaf(g.w, u3.z, acc2[i][2]);
                acc2[i][3] = fmaf(g.w, u3.w, acc2[i][3]);
            }
        }

        #pragma unroll
        for (int i = 0; i < 4; i++) {
            int gr = row0 + r2 * 4 + i;
            if (gr < N) {
                float4 pk = make_float4(acc2[i][0] + obv.x, acc2[i][1] + obv.y,
                                        acc2[i][2] + obv.z, acc2[i][3] + obv.w);
                *(float4*)&out[(size_t)gr * D + c2 * 4] = pk;
            }
        }
    }
}

// ---------------------------------------------------------------------------
extern "C" void kernel_launch(void* const* d_in, const int* in_sizes, int n_in,
                              void* d_out, int out_size, void* d_ws, size_t ws_size,
                              hipStream_t stream)
{
    const float* nf    = (const float*)d_in[0];
    const int*   ef    = (const int*)d_in[1];
    const int*   ei    = (const int*)d_in[2];
    const float* epsp  = (const float*)d_in[5];
    const float* be0   = (const float*)d_in[6];
    const float* be1   = (const float*)d_in[7];
    const float* be2   = (const float*)d_in[8];
    const float* W1    = (const float*)d_in[9];
    const float* b1    = (const float*)d_in[10];
    const float* gamma = (const float*)d_in[11];
    const float* beta  = (const float*)d_in[12];
    const float* W2    = (const float*)d_in[13];
    const float* b2v   = (const float*)d_in[14];
    float*       out   = (float*)d_out;

    int N = in_sizes[0] / D;    // 100000
    int E = in_sizes[1] / 3;    // 1600000

    int tiles2 = (N + 127) / 128;         // 782 (128-row tiles)

    // workspace layout (4-byte elements); per-bucket tri-M/s partials live
    // in-place in the payload region (dead after k_sortred's LDS sort)
    float* h       = (float*)d_ws;                    // N*64
    float* Mbar    = h + (size_t)N * D;               // 4224: full M + sbar
    float* ss      = Mbar + 4224;                     // 256
    float* embsum  = ss + 256;                        // 60*64
    int*   bcursor = (int*)(embsum + 60 * D);         // NBK*16 (line-padded)
    int*   payload = bcursor + NBK * 16;              // NBK*CAP (8.9 MB)
    float* pM      = (float*)payload;                 // stride CAP per bucket

    k_embsum<<<142, 64, 0, stream>>>(be0, be1, be2, embsum, bcursor, Mbar);

    int E2 = (E + 1) / 2;
    int gP = (E2 + 2047) / 2048;          // 391 tiles of 4096 edges
    k_part<<<gP, 512, 0, stream>>>(ei, ef, bcursor, payload, E);

    k_sortred<<<NBK, 512, 0, stream>>>(nf, bcursor, payload, embsum, epsp, h, N);

    k_redM<<<260, 512, 0, stream>>>(pM, Mbar, 1.0f / (float)N);
    k_bn<<<128, 64, 0, stream>>>(Mbar, W1, b1, gamma, beta, ss);

    k_gemm2<<<256, 512, 0, stream>>>(h, W1, b1, ss, W2, b2v, out, N, tiles2);
}